// Round 1
// baseline (160.075 us; speedup 1.0000x reference)
//
#include <hip/hip_runtime.h>
#include <math.h>

#define N_NODES 1024
#define F_DIM   128
#define M_DIM   256
#define E_DIM   8
#define P_PAIRS 523776   // N*(N-1)/2

// ---------- Kernel A: pa/pb = x @ W1a.T / x @ W1b.T, plus per-node stress ----------
// 4 nodes per block (amortize W1 row streaming 4x), 256 threads = one m each.
__global__ __launch_bounds__(256) void kA(const float* __restrict__ x,
                                          const float* __restrict__ W1,
                                          float* __restrict__ pa,
                                          float* __restrict__ pb,
                                          float* __restrict__ stress) {
  __shared__ float xv[4][128];
  const int t  = threadIdx.x;
  const int n0 = blockIdx.x * 4;
  if (t < 128) {
    ((float4*)&xv[0][0])[t] = ((const float4*)(x + (size_t)n0 * F_DIM))[t];
  }
  __syncthreads();

  // stress (torch unbiased std over features): one wave per node
  {
    const int wv = t >> 6, lane = t & 63;
    const float a = xv[wv][lane], b = xv[wv][lane + 64];
    float sum = a + b;
    #pragma unroll
    for (int m = 32; m > 0; m >>= 1) sum += __shfl_xor(sum, m, 64);
    const float mean = sum * (1.0f / 128.0f);
    const float d0 = a - mean, d1 = b - mean;
    float ss = d0 * d0 + d1 * d1;
    #pragma unroll
    for (int m = 32; m > 0; m >>= 1) ss += __shfl_xor(ss, m, 64);
    if (lane == 0) stress[n0 + wv] = sqrtf(ss * (1.0f / 127.0f));
  }

  const int m = t;
  const float4* wrow = (const float4*)(W1 + (size_t)m * 260);  // W1 row-major [256][260]
  float accA[4] = {0.f, 0.f, 0.f, 0.f};
  float accB[4] = {0.f, 0.f, 0.f, 0.f};
  #pragma unroll 8
  for (int k4 = 0; k4 < 32; ++k4) {
    const float4 wa = wrow[k4];
    const float4 wb = wrow[32 + k4];
    #pragma unroll
    for (int nn = 0; nn < 4; ++nn) {
      const float4 xf = ((const float4*)&xv[nn][0])[k4];
      accA[nn] = fmaf(xf.w, wa.w, fmaf(xf.z, wa.z, fmaf(xf.y, wa.y, fmaf(xf.x, wa.x, accA[nn]))));
      accB[nn] = fmaf(xf.w, wb.w, fmaf(xf.z, wb.z, fmaf(xf.y, wb.y, fmaf(xf.x, wb.x, accB[nn]))));
    }
  }
  #pragma unroll
  for (int nn = 0; nn < 4; ++nn) {
    pa[(size_t)(n0 + nn) * M_DIM + m] = accA[nn];
    pb[(size_t)(n0 + nn) * M_DIM + m] = accB[nn];
  }
}

// ---------- Kernel B1: cterm, BN fold (W2f transposed [m][e], b2f) ----------
__global__ __launch_bounds__(256) void kB1(const float* __restrict__ ctx,
                                           const float* __restrict__ W1,
                                           const float* __restrict__ b1,
                                           const float* __restrict__ gamma,
                                           const float* __restrict__ beta,
                                           const float* __restrict__ rmean,
                                           const float* __restrict__ rvar,
                                           const float* __restrict__ W2,
                                           const float* __restrict__ b2,
                                           float* __restrict__ cterm,
                                           float* __restrict__ w2ft,
                                           float* __restrict__ b2f) {
  __shared__ float bnbs[256];
  const int m = threadIdx.x;
  const float c0 = ctx[0], c1 = ctx[1], c2 = ctx[2], c3 = ctx[3];
  const float* row = W1 + (size_t)m * 260 + 256;
  cterm[m] = b1[m] + c0 * row[0] + c1 * row[1] + c2 * row[2] + c3 * row[3];
  const float s   = gamma[m] / sqrtf(rvar[m] + 1e-5f);
  const float bnb = beta[m] - s * rmean[m];
  bnbs[m] = bnb;
  #pragma unroll
  for (int e = 0; e < 8; ++e) w2ft[m * 8 + e] = W2[e * 256 + m] * s;
  __syncthreads();
  if (m < 8) {
    float acc = b2[m];
    for (int k = 0; k < 256; ++k) acc += W2[m * 256 + k] * bnbs[k];
    b2f[m] = acc;
  }
}

// ---------- Kernel B2: stressed flags (stress > mean(stress)) ----------
__global__ __launch_bounds__(1024) void kB2(const float* __restrict__ stress,
                                            float* __restrict__ sflag) {
  __shared__ float red[1024];
  const int t = threadIdx.x;
  const float v = stress[t];
  red[t] = v;
  __syncthreads();
  for (int s = 512; s > 0; s >>= 1) {
    if (t < s) red[t] += red[t + s];
    __syncthreads();
  }
  const float mean = red[0] * (1.0f / 1024.0f);
  sflag[t] = (v > mean) ? 1.0f : 0.0f;
}

// ---------- Kernel C: all pairs. 32x32 node tile / block, 2x2 pairs / thread ----------
// LDS: pa-tile and pb-tile, 32 rows x 256 floats, column-rotate swizzle per row
// (row stride 1024B aliases all rows to the same banks; rotation spreads them).
__global__ __launch_bounds__(256) void kC(const float* __restrict__ pa,
                                          const float* __restrict__ pb,
                                          const float* __restrict__ cterm,
                                          const float* __restrict__ w2ft,
                                          const float* __restrict__ b2f,
                                          const float* __restrict__ W3,
                                          const float* __restrict__ b3,
                                          const float* __restrict__ sflag,
                                          float* __restrict__ out) {
  const int ti = blockIdx.x, tj = blockIdx.y;
  if (tj < ti) return;  // only upper-triangular tiles
  __shared__ float paT[32 * 256];
  __shared__ float pbT[32 * 256];
  const int t  = threadIdx.x;
  const int i0 = ti * 32, j0 = tj * 32;
  float4* paT4 = (float4*)paT;
  float4* pbT4 = (float4*)pbT;

  // stage tiles (cterm folded into pa rows)
  #pragma unroll
  for (int p = 0; p < 8; ++p) {
    const int idx = p * 256 + t;
    const int row = idx >> 6;       // 0..31
    const int c4  = idx & 63;       // float4 column 0..63
    const int sc4 = (c4 + row) & 63;
    const float4 ct = ((const float4*)cterm)[c4];
    float4 av = ((const float4*)(pa + (size_t)(i0 + row) * M_DIM))[c4];
    av.x += ct.x; av.y += ct.y; av.z += ct.z; av.w += ct.w;
    paT4[row * 64 + sc4] = av;
    pbT4[row * 64 + sc4] = ((const float4*)(pb + (size_t)(j0 + row) * M_DIM))[c4];
  }
  __syncthreads();

  const int jx = t & 15;   // j within tile (coalesced stores over jx)
  const int iy = t >> 4;   // i within tile
  float acc[4][8];         // [pair 00,01,10,11][e]
  #pragma unroll
  for (int p = 0; p < 4; ++p)
    #pragma unroll
    for (int e = 0; e < 8; ++e) acc[p][e] = 0.f;

  for (int m4 = 0; m4 < 64; ++m4) {
    const float4 a0 = paT4[iy * 64 + ((m4 + iy) & 63)];
    const float4 a1 = paT4[(iy + 16) * 64 + ((m4 + iy + 16) & 63)];
    const float4 b0 = pbT4[jx * 64 + ((m4 + jx) & 63)];
    const float4 b1 = pbT4[(jx + 16) * 64 + ((m4 + jx + 16) & 63)];
    // wave-uniform address -> scalar loads (SMEM), no VALU/LDS cost
    const float4* wp = (const float4*)(w2ft + m4 * 32);
    float4 w[8];
    #pragma unroll
    for (int q = 0; q < 8; ++q) w[q] = wp[q];

    const float* a0f = (const float*)&a0;
    const float* a1f = (const float*)&a1;
    const float* b0f = (const float*)&b0;
    const float* b1f = (const float*)&b1;
    #pragma unroll
    for (int mm = 0; mm < 4; ++mm) {
      const float r00 = fmaxf(a0f[mm] + b0f[mm], 0.f);
      const float r01 = fmaxf(a0f[mm] + b1f[mm], 0.f);
      const float r10 = fmaxf(a1f[mm] + b0f[mm], 0.f);
      const float r11 = fmaxf(a1f[mm] + b1f[mm], 0.f);
      const float* wl = (const float*)&w[mm * 2];      // e 0..3
      const float* wh = (const float*)&w[mm * 2 + 1];  // e 4..7
      #pragma unroll
      for (int e = 0; e < 4; ++e) {
        acc[0][e]     = fmaf(wl[e], r00, acc[0][e]);
        acc[1][e]     = fmaf(wl[e], r01, acc[1][e]);
        acc[2][e]     = fmaf(wl[e], r10, acc[2][e]);
        acc[3][e]     = fmaf(wl[e], r11, acc[3][e]);
        acc[0][e + 4] = fmaf(wh[e], r00, acc[0][e + 4]);
        acc[1][e + 4] = fmaf(wh[e], r01, acc[1][e + 4]);
        acc[2][e + 4] = fmaf(wh[e], r10, acc[2][e + 4]);
        acc[3][e + 4] = fmaf(wh[e], r11, acc[3][e + 4]);
      }
    }
  }

  // epilogue: second relu, W3 dot, sigmoid, mask, triu-ordered store
  float w3v[8], b2v[8];
  #pragma unroll
  for (int e = 0; e < 8; ++e) { w3v[e] = W3[e]; b2v[e] = b2f[e]; }
  const float b3v = b3[0];
  #pragma unroll
  for (int ia = 0; ia < 2; ++ia) {
    #pragma unroll
    for (int jb = 0; jb < 2; ++jb) {
      const int i = i0 + iy + ia * 16;
      const int j = j0 + jx + jb * 16;
      if (i < j) {
        const int p = ia * 2 + jb;
        float logit = b3v;
        #pragma unroll
        for (int e = 0; e < 8; ++e) {
          const float h2 = fmaxf(acc[p][e] + b2v[e], 0.f);
          logit = fmaf(w3v[e], h2, logit);
        }
        const float score = 1.0f / (1.0f + expf(-logit));
        const int idx = i * 1023 - (i * (i - 1)) / 2 + (j - i - 1);
        out[idx] = score;
        const bool mk = (score > 0.5f) && (sflag[i] > 0.5f) && (sflag[j] > 0.5f);
        out[P_PAIRS + idx] = mk ? 1.0f : 0.0f;
      }
    }
  }
}

extern "C" void kernel_launch(void* const* d_in, const int* in_sizes, int n_in,
                              void* d_out, int out_size, void* d_ws, size_t ws_size,
                              hipStream_t stream) {
  const float* x     = (const float*)d_in[0];
  const float* ctx   = (const float*)d_in[1];
  const float* W1    = (const float*)d_in[2];
  const float* b1    = (const float*)d_in[3];
  const float* gamma = (const float*)d_in[4];
  const float* beta  = (const float*)d_in[5];
  const float* rmean = (const float*)d_in[6];
  const float* rvar  = (const float*)d_in[7];
  const float* W2    = (const float*)d_in[8];
  const float* b2    = (const float*)d_in[9];
  const float* W3    = (const float*)d_in[10];
  const float* b3    = (const float*)d_in[11];
  float* out = (float*)d_out;

  float* ws     = (float*)d_ws;
  float* pa     = ws;              // 1024*256
  float* pb     = pa + 262144;     // 1024*256
  float* cterm  = pb + 262144;     // 256
  float* w2ft   = cterm + 256;     // 256*8 (transposed [m][e])
  float* b2f    = w2ft + 2048;     // 8
  float* stress = b2f + 8;         // 1024
  float* sflag  = stress + 1024;   // 1024

  hipLaunchKernelGGL(kA,  dim3(256),    dim3(256),  0, stream, x, W1, pa, pb, stress);
  hipLaunchKernelGGL(kB1, dim3(1),      dim3(256),  0, stream, ctx, W1, b1, gamma, beta,
                     rmean, rvar, W2, b2, cterm, w2ft, b2f);
  hipLaunchKernelGGL(kB2, dim3(1),      dim3(1024), 0, stream, stress, sflag);
  hipLaunchKernelGGL(kC,  dim3(32, 32), dim3(256),  0, stream, pa, pb, cterm, w2ft, b2f,
                     W3, b3, sflag, out);
}

// Round 2
// 153.965 us; speedup vs baseline: 1.0397x; 1.0397x over previous
//
#include <hip/hip_runtime.h>
#include <math.h>

#define N_NODES 1024
#define F_DIM   128
#define M_DIM   256
#define E_DIM   8
#define P_PAIRS 523776   // N*(N-1)/2

// ---------- Kernel A: pa/pb = x @ W1a.T / x @ W1b.T, plus per-node stress ----------
__global__ __launch_bounds__(256) void kA(const float* __restrict__ x,
                                          const float* __restrict__ W1,
                                          float* __restrict__ pa,
                                          float* __restrict__ pb,
                                          float* __restrict__ stress) {
  __shared__ float xv[4][128];
  const int t  = threadIdx.x;
  const int n0 = blockIdx.x * 4;
  if (t < 128) {
    ((float4*)&xv[0][0])[t] = ((const float4*)(x + (size_t)n0 * F_DIM))[t];
  }
  __syncthreads();

  // stress (torch unbiased std over features): one wave per node
  {
    const int wv = t >> 6, lane = t & 63;
    const float a = xv[wv][lane], b = xv[wv][lane + 64];
    float sum = a + b;
    #pragma unroll
    for (int m = 32; m > 0; m >>= 1) sum += __shfl_xor(sum, m, 64);
    const float mean = sum * (1.0f / 128.0f);
    const float d0 = a - mean, d1 = b - mean;
    float ss = d0 * d0 + d1 * d1;
    #pragma unroll
    for (int m = 32; m > 0; m >>= 1) ss += __shfl_xor(ss, m, 64);
    if (lane == 0) stress[n0 + wv] = sqrtf(ss * (1.0f / 127.0f));
  }

  const int m = t;
  const float4* wrow = (const float4*)(W1 + (size_t)m * 260);  // W1 row-major [256][260]
  float accA[4] = {0.f, 0.f, 0.f, 0.f};
  float accB[4] = {0.f, 0.f, 0.f, 0.f};
  #pragma unroll 8
  for (int k4 = 0; k4 < 32; ++k4) {
    const float4 wa = wrow[k4];
    const float4 wb = wrow[32 + k4];
    #pragma unroll
    for (int nn = 0; nn < 4; ++nn) {
      const float4 xf = ((const float4*)&xv[nn][0])[k4];
      accA[nn] = fmaf(xf.w, wa.w, fmaf(xf.z, wa.z, fmaf(xf.y, wa.y, fmaf(xf.x, wa.x, accA[nn]))));
      accB[nn] = fmaf(xf.w, wb.w, fmaf(xf.z, wb.z, fmaf(xf.y, wb.y, fmaf(xf.x, wb.x, accB[nn]))));
    }
  }
  #pragma unroll
  for (int nn = 0; nn < 4; ++nn) {
    pa[(size_t)(n0 + nn) * M_DIM + m] = accA[nn];
    pb[(size_t)(n0 + nn) * M_DIM + m] = accB[nn];
  }
}

// ---------- Kernel B (merged): cterm, BN fold, b2f (parallel), stressed flags ----------
__global__ __launch_bounds__(1024) void kB(const float* __restrict__ ctx,
                                           const float* __restrict__ W1,
                                           const float* __restrict__ b1,
                                           const float* __restrict__ gamma,
                                           const float* __restrict__ beta,
                                           const float* __restrict__ rmean,
                                           const float* __restrict__ rvar,
                                           const float* __restrict__ W2,
                                           const float* __restrict__ b2,
                                           const float* __restrict__ stress,
                                           float* __restrict__ cterm,
                                           float* __restrict__ w2ft,
                                           float* __restrict__ b2f,
                                           float* __restrict__ sflag) {
  __shared__ float bnbs[256];
  __shared__ float red[1024];
  const int t = threadIdx.x;

  if (t < 256) {
    const float c0 = ctx[0], c1 = ctx[1], c2 = ctx[2], c3 = ctx[3];
    const float* row = W1 + (size_t)t * 260 + 256;
    cterm[t] = b1[t] + c0 * row[0] + c1 * row[1] + c2 * row[2] + c3 * row[3];
    const float s   = gamma[t] / sqrtf(rvar[t] + 1e-5f);
    const float bnb = beta[t] - s * rmean[t];
    bnbs[t] = bnb;
    #pragma unroll
    for (int e = 0; e < 8; ++e) w2ft[t * 8 + e] = W2[e * 256 + t] * s;
  }

  // stress mean + flags (same tree order as before)
  const float v = stress[t];
  red[t] = v;
  __syncthreads();
  for (int s2 = 512; s2 > 0; s2 >>= 1) {
    if (t < s2) red[t] += red[t + s2];
    __syncthreads();
  }
  const float mean = red[0] * (1.0f / 1024.0f);
  sflag[t] = (v > mean) ? 1.0f : 0.0f;

  // b2f: wave e (0..7) reduces sum_k W2[e][k]*bnb[k] (exact: bnb==0 when rmean=0,beta=0;
  // order-insensitive in general up to 1e-7 on a folded bias term)
  const int wv = t >> 6, lane = t & 63;
  if (wv < 8) {
    float acc = 0.f;
    #pragma unroll
    for (int k = 0; k < 4; ++k) acc += W2[wv * 256 + lane + k * 64] * bnbs[lane + k * 64];
    #pragma unroll
    for (int m = 32; m > 0; m >>= 1) acc += __shfl_xor(acc, m, 64);
    if (lane == 0) b2f[wv] = acc + b2[wv];
  }
}

// ---------- Kernel C: all pairs. 32x32 node tile / block, 2x2 pairs / thread ----------
__global__ __launch_bounds__(256) void kC(const float* __restrict__ pa,
                                          const float* __restrict__ pb,
                                          const float* __restrict__ cterm,
                                          const float* __restrict__ w2ft,
                                          const float* __restrict__ b2f,
                                          const float* __restrict__ W3,
                                          const float* __restrict__ b3,
                                          const float* __restrict__ sflag,
                                          float* __restrict__ out) {
  const int ti = blockIdx.x, tj = blockIdx.y;
  if (tj < ti) return;  // only upper-triangular tiles
  __shared__ float paT[32 * 256];
  __shared__ float pbT[32 * 256];
  __shared__ float wsh[2048];      // w2ft staged: in-loop reads are same-address broadcast
  const int t  = threadIdx.x;
  const int i0 = ti * 32, j0 = tj * 32;
  float4* paT4 = (float4*)paT;
  float4* pbT4 = (float4*)pbT;

  ((float4*)wsh)[t]       = ((const float4*)w2ft)[t];
  ((float4*)wsh)[256 + t] = ((const float4*)w2ft)[256 + t];

  // stage tiles (cterm folded into pa rows), column-rotate swizzle per row
  #pragma unroll
  for (int p = 0; p < 8; ++p) {
    const int idx = p * 256 + t;
    const int row = idx >> 6;       // 0..31
    const int c4  = idx & 63;       // float4 column 0..63
    const int sc4 = (c4 + row) & 63;
    const float4 ct = ((const float4*)cterm)[c4];
    float4 av = ((const float4*)(pa + (size_t)(i0 + row) * M_DIM))[c4];
    av.x += ct.x; av.y += ct.y; av.z += ct.z; av.w += ct.w;
    paT4[row * 64 + sc4] = av;
    pbT4[row * 64 + sc4] = ((const float4*)(pb + (size_t)(j0 + row) * M_DIM))[c4];
  }
  __syncthreads();

  const int jx = t & 15;   // j within tile (coalesced stores over jx)
  const int iy = t >> 4;   // i within tile
  float acc[4][8];         // [pair 00,01,10,11][e]
  #pragma unroll
  for (int p = 0; p < 4; ++p)
    #pragma unroll
    for (int e = 0; e < 8; ++e) acc[p][e] = 0.f;

  #pragma unroll 2
  for (int m4 = 0; m4 < 64; ++m4) {
    const float4 a0 = paT4[iy * 64 + ((m4 + iy) & 63)];
    const float4 a1 = paT4[(iy + 16) * 64 + ((m4 + iy + 16) & 63)];
    const float4 b0 = pbT4[jx * 64 + ((m4 + jx) & 63)];
    const float4 b1 = pbT4[(jx + 16) * 64 + ((m4 + jx + 16) & 63)];
    const float4* wp = (const float4*)(wsh + m4 * 32);
    float4 w[8];
    #pragma unroll
    for (int q = 0; q < 8; ++q) w[q] = wp[q];

    const float* a0f = (const float*)&a0;
    const float* a1f = (const float*)&a1;
    const float* b0f = (const float*)&b0;
    const float* b1f = (const float*)&b1;
    #pragma unroll
    for (int mm = 0; mm < 4; ++mm) {
      const float r00 = fmaxf(a0f[mm] + b0f[mm], 0.f);
      const float r01 = fmaxf(a0f[mm] + b1f[mm], 0.f);
      const float r10 = fmaxf(a1f[mm] + b0f[mm], 0.f);
      const float r11 = fmaxf(a1f[mm] + b1f[mm], 0.f);
      const float* wl = (const float*)&w[mm * 2];      // e 0..3
      const float* wh = (const float*)&w[mm * 2 + 1];  // e 4..7
      #pragma unroll
      for (int e = 0; e < 4; ++e) {
        acc[0][e]     = fmaf(wl[e], r00, acc[0][e]);
        acc[1][e]     = fmaf(wl[e], r01, acc[1][e]);
        acc[2][e]     = fmaf(wl[e], r10, acc[2][e]);
        acc[3][e]     = fmaf(wl[e], r11, acc[3][e]);
        acc[0][e + 4] = fmaf(wh[e], r00, acc[0][e + 4]);
        acc[1][e + 4] = fmaf(wh[e], r01, acc[1][e + 4]);
        acc[2][e + 4] = fmaf(wh[e], r10, acc[2][e + 4]);
        acc[3][e + 4] = fmaf(wh[e], r11, acc[3][e + 4]);
      }
    }
  }

  // epilogue: second relu, W3 dot, sigmoid, mask, triu-ordered store
  float w3v[8], b2v[8];
  #pragma unroll
  for (int e = 0; e < 8; ++e) { w3v[e] = W3[e]; b2v[e] = b2f[e]; }
  const float b3v = b3[0];
  #pragma unroll
  for (int ia = 0; ia < 2; ++ia) {
    #pragma unroll
    for (int jb = 0; jb < 2; ++jb) {
      const int i = i0 + iy + ia * 16;
      const int j = j0 + jx + jb * 16;
      if (i < j) {
        const int p = ia * 2 + jb;
        float logit = b3v;
        #pragma unroll
        for (int e = 0; e < 8; ++e) {
          const float h2 = fmaxf(acc[p][e] + b2v[e], 0.f);
          logit = fmaf(w3v[e], h2, logit);
        }
        const float score = 1.0f / (1.0f + expf(-logit));
        const int idx = i * 1023 - (i * (i - 1)) / 2 + (j - i - 1);
        out[idx] = score;
        const bool mk = (score > 0.5f) && (sflag[i] > 0.5f) && (sflag[j] > 0.5f);
        out[P_PAIRS + idx] = mk ? 1.0f : 0.0f;
      }
    }
  }
}

extern "C" void kernel_launch(void* const* d_in, const int* in_sizes, int n_in,
                              void* d_out, int out_size, void* d_ws, size_t ws_size,
                              hipStream_t stream) {
  const float* x     = (const float*)d_in[0];
  const float* ctx   = (const float*)d_in[1];
  const float* W1    = (const float*)d_in[2];
  const float* b1    = (const float*)d_in[3];
  const float* gamma = (const float*)d_in[4];
  const float* beta  = (const float*)d_in[5];
  const float* rmean = (const float*)d_in[6];
  const float* rvar  = (const float*)d_in[7];
  const float* W2    = (const float*)d_in[8];
  const float* b2    = (const float*)d_in[9];
  const float* W3    = (const float*)d_in[10];
  const float* b3    = (const float*)d_in[11];
  float* out = (float*)d_out;

  float* ws     = (float*)d_ws;
  float* pa     = ws;              // 1024*256
  float* pb     = pa + 262144;     // 1024*256
  float* cterm  = pb + 262144;     // 256
  float* w2ft   = cterm + 256;     // 256*8 (transposed [m][e])
  float* b2f    = w2ft + 2048;     // 8
  float* stress = b2f + 8;         // 1024
  float* sflag  = stress + 1024;   // 1024

  hipLaunchKernelGGL(kA, dim3(256),    dim3(256),  0, stream, x, W1, pa, pb, stress);
  hipLaunchKernelGGL(kB, dim3(1),      dim3(1024), 0, stream, ctx, W1, b1, gamma, beta,
                     rmean, rvar, W2, b2, stress, cterm, w2ft, b2f, sflag);
  hipLaunchKernelGGL(kC, dim3(32, 32), dim3(256),  0, stream, pa, pb, cterm, w2ft, b2f,
                     W3, b3, sflag, out);
}